// Round 3
// baseline (347.550 us; speedup 1.0000x reference)
//
#include <hip/hip_runtime.h>

#define B_DIM 4096
#define T_DIM 200
#define D_DIM 128
#define H_DIM 16
#define TT    64            // t-tile
#define NTILE 4             // ceil(200/64)
#define FSTR  132           // padded floats per LDS facts row
// fbuf + weff + qrow + qw + scr + pad  (single-buffered fbuf -> 3 blocks/CU)
#define SMEM_FLOATS (TT*FSTR + H_DIM*D_DIM + D_DIM + H_DIM + 512 + 4)

__device__ __forceinline__ float sigmoidf_(float x) { return 1.f / (1.f + __expf(-x)); }

extern "C" __global__ __launch_bounds__(256, 3)
void din_fused(const float* __restrict__ query,
               const float* __restrict__ facts,
               const int* __restrict__ mask,
               const float* __restrict__ W1,
               const float* __restrict__ b1,
               const float* __restrict__ W2,
               float* __restrict__ out)
{
    const int b    = blockIdx.x;
    const int tid  = threadIdx.x;
    const int lane = tid & 63;
    extern __shared__ __align__(16) float smem[];
    float* fbuf = smem;                       // [TT*FSTR] facts tile (single buffer)
    float* weff = smem + TT*FSTR;             // [H][D] effective weights
    float* qrow = weff + H_DIM*D_DIM;         // [128]
    float* qw   = qrow + D_DIM;               // [16]
    float* scr  = qw + H_DIM;                 // [512] scoring partials / epilogue scratch

    const size_t fbase = (size_t)b * T_DIM * D_DIM;

    // ---- prologue: q row + tile0 prefetch (regs) ----
    if (tid < D_DIM) qrow[tid] = query[(size_t)b * D_DIM + tid];

    float4 r[8];
    #pragma unroll
    for (int k = 0; k < 8; ++k) {
        int f4 = tid + 256 * k;
        int tt = f4 >> 5, cc = f4 & 31;
        r[k] = *(const float4*)&facts[fbase + (size_t)tt * D_DIM + 4 * cc];
    }
    __syncthreads();   // qrow ready

    // ---- W_eff[h][d] = (W1b - W1c)[d][h] + q_d * W1d[d][h] ----
    #pragma unroll
    for (int k = 0; k < 8; ++k) {
        int idx = tid + 256 * k;              // idx = h*128 + d
        int d = idx & 127, h = idx >> 7;
        weff[idx] = W1[(128 + d) * H_DIM + h] - W1[(256 + d) * H_DIM + h]
                  + qrow[d] * W1[(384 + d) * H_DIM + h];
    }
    {   // qW partials
        int h = tid & 15, g = tid >> 4;
        float p = 0.f;
        #pragma unroll
        for (int j = 0; j < 8; ++j) {
            int d = 8 * g + j;
            p += qrow[d] * (W1[d * H_DIM + h] + W1[(256 + d) * H_DIM + h]);
        }
        scr[tid] = p;
    }
    // commit tile0 to LDS
    #pragma unroll
    for (int k = 0; k < 8; ++k) {
        int f4 = tid + 256 * k;
        int tt = f4 >> 5, cc = f4 & 31;
        *(float4*)&fbuf[tt * FSTR + 4 * cc] = r[k];
    }
    __syncthreads();   // weff, scr partials, tile0 ready
    if (tid < H_DIM) {
        float s = b1[tid];
        #pragma unroll
        for (int g = 0; g < 16; ++g) s += scr[g * 16 + tid];
        qw[tid] = s;
    }
    __syncthreads();   // qw ready

    const int   t2  = tid & 31;               // scoring: t in {t2, t2+32}
    const int   h2  = tid >> 5;               // scoring: h in {h2, h2+8}
    const float w2a = W2[h2], w2b = W2[h2 + 8];
    const float qwa = qw[h2], qwb = qw[h2 + 8];
    const int   c4  = tid & 31;               // acc phase: float4 column
    const int   tg8 = tid >> 5;               // acc phase: t in [8*tg8, 8*tg8+8)

    float4 acc = make_float4(0.f, 0.f, 0.f, 0.f);
    float m = -3e38f, l = 0.f;

    for (int it = 0; it < NTILE; ++it) {
        const bool pf = (it + 1 < NTILE);
        if (pf) {  // issue next tile's global loads early (latency hides under scoring)
            int t0n = (it + 1) * TT;
            #pragma unroll
            for (int k = 0; k < 8; ++k) {
                int f4 = tid + 256 * k;
                int tt = f4 >> 5, cc = f4 & 31;
                int tg = t0n + tt; if (tg > T_DIM - 1) tg = T_DIM - 1;
                r[k] = *(const float4*)&facts[fbase + (size_t)tg * D_DIM + 4 * cc];
            }
        }

        // ---- scoring: pre[t][h] = qW[h] + f_t . W_eff[h] ----
        float a00 = qwa, a01 = qwb, a10 = qwa, a11 = qwb;
        #pragma unroll 8
        for (int k = 0; k < 32; ++k) {
            float4 f0 = *(const float4*)&fbuf[t2 * FSTR + 4 * k];
            float4 f1 = *(const float4*)&fbuf[(t2 + 32) * FSTR + 4 * k];
            float4 wa = *(const float4*)&weff[h2 * D_DIM + 4 * k];
            float4 wb = *(const float4*)&weff[(h2 + 8) * D_DIM + 4 * k];
            a00 += f0.x * wa.x + f0.y * wa.y + f0.z * wa.z + f0.w * wa.w;
            a01 += f0.x * wb.x + f0.y * wb.y + f0.z * wb.z + f0.w * wb.w;
            a10 += f1.x * wa.x + f1.y * wa.y + f1.z * wa.z + f1.w * wa.w;
            a11 += f1.x * wb.x + f1.y * wb.y + f1.z * wb.z + f1.w * wb.w;
        }
        float p0 = sigmoidf_(a00) * w2a + sigmoidf_(a01) * w2b;
        float p1 = sigmoidf_(a10) * w2a + sigmoidf_(a11) * w2b;
        scr[h2 * 64 + t2]      = p0;
        scr[h2 * 64 + t2 + 32] = p1;
        __syncthreads();                              // B1: partials in scr

        // ---- softmax: ALL waves compute redundantly (deterministic, identical) ----
        float s = 0.f;
        #pragma unroll
        for (int hh = 0; hh < 8; ++hh) s += scr[hh * 64 + lane];
        int tglob = it * TT + lane;
        bool valid = (tglob < T_DIM) && (mask[(size_t)b * T_DIM + tglob] != 0);
        s = valid ? s : -1e30f;
        float mt = s;
        #pragma unroll
        for (int off = 32; off; off >>= 1) mt = fmaxf(mt, __shfl_xor(mt, off));
        float nm = fmaxf(m, mt);
        float w = valid ? __expf(s - nm) : 0.f;       // lane holds weight of t = it*64+lane
        float S = w;
        #pragma unroll
        for (int off = 32; off; off >>= 1) S += __shfl_xor(S, off);
        float fac = __expf(m - nm);                   // first tile: exp(-3e38)=0, no NaN
        m = nm;
        l = l * fac + S;
        acc.x *= fac; acc.y *= fac; acc.z *= fac; acc.w *= fac;

        // ---- weighted sum from resident tile (weights via in-wave shfl) ----
        #pragma unroll
        for (int j = 0; j < 8; ++j) {
            int tt = 8 * tg8 + j;
            float wgt = __shfl(w, tt & 63);           // source lane holds w of this t
            float4 f = *(const float4*)&fbuf[tt * FSTR + 4 * c4];
            acc.x += wgt * f.x; acc.y += wgt * f.y; acc.z += wgt * f.z; acc.w += wgt * f.w;
        }

        if (pf) {
            __syncthreads();                          // B2: fbuf/scr fully consumed
            #pragma unroll
            for (int k = 0; k < 8; ++k) {
                int f4 = tid + 256 * k;
                int tt = f4 >> 5, cc = f4 & 31;
                *(float4*)&fbuf[tt * FSTR + 4 * cc] = r[k];
            }
            __syncthreads();                          // B3: next tile ready
        }
    }

    // ---- epilogue: combine 8 t-group partials, divide by l ----
    __syncthreads();                                  // scr safe to overwrite
    float4 a = acc;
    a.x += __shfl_xor(a.x, 32);
    a.y += __shfl_xor(a.y, 32);
    a.z += __shfl_xor(a.z, 32);
    a.w += __shfl_xor(a.w, 32);
    int wv = tid >> 6;
    if (lane < 32) *(float4*)&scr[wv * 128 + 4 * lane] = a;
    __syncthreads();
    if (tid < D_DIM) {
        float o = scr[tid] + scr[128 + tid] + scr[256 + tid] + scr[384 + tid];
        out[(size_t)b * D_DIM + tid] = o / l;
    }
}

extern "C" void kernel_launch(void* const* d_in, const int* in_sizes, int n_in,
                              void* d_out, int out_size, void* d_ws, size_t ws_size,
                              hipStream_t stream) {
    const float* query = (const float*)d_in[0];
    const float* facts = (const float*)d_in[1];
    const int*   mask  = (const int*)d_in[2];     // harness delivers bool as int32
    const float* W1    = (const float*)d_in[3];
    const float* b1    = (const float*)d_in[4];
    const float* W2    = (const float*)d_in[5];
    // d_in[6] = b2: dropped (softmax shift-invariant)
    float* out = (float*)d_out;
    (void)in_sizes; (void)n_in; (void)out_size; (void)d_ws; (void)ws_size;

    size_t smem_bytes = SMEM_FLOATS * sizeof(float);   // 44,624 B -> 3 blocks/CU
    hipFuncSetAttribute((const void*)din_fused,
                        hipFuncAttributeMaxDynamicSharedMemorySize, (int)smem_bytes);
    din_fused<<<dim3(B_DIM), dim3(256), smem_bytes, stream>>>(
        query, facts, mask, W1, b1, W2, out);
}

// Round 4
// 341.672 us; speedup vs baseline: 1.0172x; 1.0172x over previous
//
#include <hip/hip_runtime.h>

#define B_DIM 4096
#define T_DIM 200
#define D_DIM 128
#define H_DIM 16
#define TT    64
#define NTILE 4

// LDS layout (floats)
#define OFF_WEFF (2*TT*D_DIM)               // fbuf[2][64][128] = 16384
#define OFF_QROW (OFF_WEFF + H_DIM*D_DIM)   // weff[16][128]
#define OFF_QW   (OFF_QROW + D_DIM)         // qrow[128]
#define OFF_SACC (OFF_QW + H_DIM)           // qw[16]
#define OFF_RED  (OFF_SACC + 4*D_DIM)       // sacc[4][128] (also qW scratch)
#define SMEM_FLOATS (OFF_RED + 8)           // red[8]

__device__ __forceinline__ float sigmoidf_(float x){ return 1.f/(1.f+__expf(-x)); }

// async global->LDS DMA: lane i writes lds[i*16B .. +16B); source addr per-lane.
__device__ __forceinline__ void gload_lds16(const float* g, float* l) {
    __builtin_amdgcn_global_load_lds(
        (const __attribute__((address_space(1))) void*)g,
        (__attribute__((address_space(3))) void*)l, 16, 0, 0);
}

extern "C" __global__ __launch_bounds__(256, 2)
void din_fused(const float* __restrict__ query,
               const float* __restrict__ facts,
               const int* __restrict__ mask,
               const float* __restrict__ W1,
               const float* __restrict__ b1,
               const float* __restrict__ W2,
               float* __restrict__ out)
{
    const int b    = blockIdx.x;
    const int tid  = threadIdx.x;
    const int wid  = tid >> 6;
    const int lane = tid & 63;
    const int hq   = tid & 3;            // owns h = 4*hq + j, and d-seg [32*hq, 32*hq+32)
    const int trow = lane >> 2;          // 0..15: row within wave
    const int row  = wid*16 + trow;      // 0..63: tile-local row this thread scores
    const int rx   = row & 7;            // LDS XOR-swizzle key

    extern __shared__ __align__(16) float smem[];
    float* fbuf = smem;
    float* weff = smem + OFF_WEFF;
    float* qrow = smem + OFF_QROW;
    float* qw   = smem + OFF_QW;
    float* sacc = smem + OFF_SACC;
    float* red  = smem + OFF_RED;

    const size_t fbase = (size_t)b * (T_DIM * D_DIM);

    // ---- stage tile 0 (DMA; swizzled source, linear LDS dest) ----
    #pragma unroll
    for (int j = 0; j < 8; ++j) {
        int chunk = wid*8 + j;                   // 1KB chunk = 2 rows
        int srow  = 2*chunk + (lane>>5);
        int u     = lane & 31;
        int kz    = u ^ (srow & 7);              // pre-swizzle source unit
        gload_lds16(&facts[fbase + (size_t)srow*D_DIM + 4*kz], &fbuf[chunk*256]);
    }
    if (tid < D_DIM) qrow[tid] = query[(size_t)b*D_DIM + tid];
    asm volatile("s_waitcnt vmcnt(0)" ::: "memory");
    __syncthreads();                             // B1: qrow + tile0 ready

    // ---- W_eff[h][d] = (W1b - W1c)[d][h] + q_d * W1d[d][h] ----
    #pragma unroll
    for (int kk = 0; kk < 8; ++kk) {
        int idx = tid + 256*kk;                  // h*128 + d
        int d = idx & 127, h = idx >> 7;
        weff[idx] = W1[(128+d)*H_DIM + h] - W1[(256+d)*H_DIM + h]
                  + qrow[d]*W1[(384+d)*H_DIM + h];
    }
    {   // qW partials into sacc (scratch use)
        int h = tid & 15, g = tid >> 4;
        float p = 0.f;
        #pragma unroll
        for (int j2 = 0; j2 < 8; ++j2) {
            int d = 8*g + j2;
            p += qrow[d]*(W1[d*H_DIM + h] + W1[(256+d)*H_DIM + h]);
        }
        sacc[tid] = p;
    }
    __syncthreads();                             // B2
    if (tid < H_DIM) {
        float s = b1[tid];
        #pragma unroll
        for (int g = 0; g < 16; ++g) s += sacc[g*16 + tid];
        qw[tid] = s;
    }
    __syncthreads();                             // B3
    float qwj[4], w2j[4];
    #pragma unroll
    for (int j = 0; j < 4; ++j) { qwj[j] = qw[4*hq+j]; w2j[j] = W2[4*hq+j]; }

    float4 acc[8];
    #pragma unroll
    for (int u = 0; u < 8; ++u) acc[u] = make_float4(0.f,0.f,0.f,0.f);
    float m = -3e38f, l = 0.f;
    int cur = 0;

    for (int it = 0; it < NTILE; ++it) {
        if (it + 1 < NTILE) {                    // DMA next tile into other buffer
            float* nb = &fbuf[(cur^1)*TT*D_DIM];
            #pragma unroll
            for (int j = 0; j < 8; ++j) {
                int chunk = wid*8 + j;
                int srow  = 2*chunk + (lane>>5);
                int u     = lane & 31;
                int kz    = u ^ (srow & 7);
                int tg    = (it+1)*TT + srow; if (tg > T_DIM-1) tg = T_DIM-1;
                gload_lds16(&facts[fbase + (size_t)tg*D_DIM + 4*kz], &nb[chunk*256]);
            }
        }
        const float* fb = &fbuf[cur*TT*D_DIM];

        // ---- scoring: thread does full 128-d dot for its 4 h's ----
        float pre0 = qwj[0], pre1 = qwj[1], pre2 = qwj[2], pre3 = qwj[3];
        #pragma unroll 4
        for (int k = 0; k < 32; ++k) {           // logical unit k, phys k^rx
            float4 f4 = *(const float4*)&fb[row*D_DIM + 4*(k ^ rx)];
            float4 w0 = *(const float4*)&weff[(4*hq+0)*D_DIM + 4*k];
            float4 w1 = *(const float4*)&weff[(4*hq+1)*D_DIM + 4*k];
            float4 w2 = *(const float4*)&weff[(4*hq+2)*D_DIM + 4*k];
            float4 w3 = *(const float4*)&weff[(4*hq+3)*D_DIM + 4*k];
            pre0 += f4.x*w0.x + f4.y*w0.y + f4.z*w0.z + f4.w*w0.w;
            pre1 += f4.x*w1.x + f4.y*w1.y + f4.z*w1.z + f4.w*w1.w;
            pre2 += f4.x*w2.x + f4.y*w2.y + f4.z*w2.z + f4.w*w2.w;
            pre3 += f4.x*w3.x + f4.y*w3.y + f4.z*w3.z + f4.w*w3.w;
        }
        float sc = sigmoidf_(pre0)*w2j[0] + sigmoidf_(pre1)*w2j[1]
                 + sigmoidf_(pre2)*w2j[2] + sigmoidf_(pre3)*w2j[3];
        sc += __shfl_xor(sc, 1);
        sc += __shfl_xor(sc, 2);                 // full score, all 4 hq lanes

        // ---- per-wave online softmax over this wave's 16 rows ----
        int tglob = it*TT + row;
        int tc    = tglob < T_DIM ? tglob : T_DIM-1;
        bool valid = (tglob < T_DIM) && (mask[(size_t)b*T_DIM + tc] != 0);
        float s = valid ? sc : -1e30f;
        float mt = s;
        #pragma unroll
        for (int off = 4; off <= 32; off <<= 1) mt = fmaxf(mt, __shfl_xor(mt, off));
        float nm  = fmaxf(m, mt);
        float wgt = valid ? __expf(s - nm) : 0.f;
        float S = wgt;
        #pragma unroll
        for (int off = 4; off <= 32; off <<= 1) S += __shfl_xor(S, off);
        float fac = __expf(m - nm);              // dead wave: exp(-inf)=0, zeroes acc
        m = nm; l = l*fac + S;

        // ---- weighted accumulate of own row into own d-segment ----
        #pragma unroll
        for (int u = 0; u < 8; ++u) {
            int ku = 8*hq + u;                   // logical unit of d = 32*hq+4u
            float4 f4 = *(const float4*)&fb[row*D_DIM + 4*(ku ^ rx)];
            acc[u].x = acc[u].x*fac + wgt*f4.x;
            acc[u].y = acc[u].y*fac + wgt*f4.y;
            acc[u].z = acc[u].z*fac + wgt*f4.z;
            acc[u].w = acc[u].w*fac + wgt*f4.w;
        }
        asm volatile("s_waitcnt vmcnt(0)" ::: "memory");
        __syncthreads();                         // B4: staging landed, swap safe
        cur ^= 1;
    }

    // ---- epilogue: reduce acc over 16 rows (in-wave), then 4-way wave merge ----
    #pragma unroll
    for (int off = 4; off <= 32; off <<= 1) {
        #pragma unroll
        for (int u = 0; u < 8; ++u) {
            acc[u].x += __shfl_xor(acc[u].x, off);
            acc[u].y += __shfl_xor(acc[u].y, off);
            acc[u].z += __shfl_xor(acc[u].z, off);
            acc[u].w += __shfl_xor(acc[u].w, off);
        }
    }
    if (trow == 0) {
        #pragma unroll
        for (int u = 0; u < 8; ++u)
            *(float4*)&sacc[wid*D_DIM + 32*hq + 4*u] = acc[u];
        if (hq == 0) { red[wid] = m; red[4+wid] = l; }
    }
    __syncthreads();                             // B5
    if (tid < D_DIM) {
        float m0=red[0], m1=red[1], m2=red[2], m3=red[3];
        float M = fmaxf(fmaxf(m0,m1), fmaxf(m2,m3));
        float e0=__expf(m0-M), e1=__expf(m1-M), e2=__expf(m2-M), e3=__expf(m3-M);
        float L = e0*red[4] + e1*red[5] + e2*red[6] + e3*red[7];
        float o = e0*sacc[tid] + e1*sacc[128+tid] + e2*sacc[256+tid] + e3*sacc[384+tid];
        out[(size_t)b*D_DIM + tid] = o / L;
    }
}

extern "C" void kernel_launch(void* const* d_in, const int* in_sizes, int n_in,
                              void* d_out, int out_size, void* d_ws, size_t ws_size,
                              hipStream_t stream) {
    const float* query = (const float*)d_in[0];
    const float* facts = (const float*)d_in[1];
    const int*   mask  = (const int*)d_in[2];   // harness delivers bool as int32
    const float* W1    = (const float*)d_in[3];
    const float* b1    = (const float*)d_in[4];
    const float* W2    = (const float*)d_in[5];
    // d_in[6] = b2: dropped (softmax shift-invariant)
    float* out = (float*)d_out;
    (void)in_sizes; (void)n_in; (void)out_size; (void)d_ws; (void)ws_size;

    size_t smem_bytes = SMEM_FLOATS * sizeof(float);   // 76,448 B -> 2 blocks/CU
    hipFuncSetAttribute((const void*)din_fused,
                        hipFuncAttributeMaxDynamicSharedMemorySize, (int)smem_bytes);
    din_fused<<<dim3(B_DIM), dim3(256), smem_bytes, stream>>>(
        query, facts, mask, W1, b1, W2, out);
}

// Round 6
// 244.139 us; speedup vs baseline: 1.4236x; 1.3995x over previous
//
#include <hip/hip_runtime.h>

#define B_DIM 4096
#define T_DIM 200
#define D_DIM 128
#define H_DIM 16

extern "C" __global__ __launch_bounds__(256, 2)
void din_fused(const float* __restrict__ query,
               const float* __restrict__ facts,
               const int* __restrict__ mask,
               const float* __restrict__ W1,
               const float* __restrict__ b1,
               const float* __restrict__ W2,
               float* __restrict__ out)
{
    const int b    = blockIdx.x;
    const int tid  = threadIdx.x;
    const int wid  = tid >> 6;
    const int lane = tid & 63;
    const int hq   = tid & 3;          // d-subset {16k + 4*hq + c}
    const int rp   = tid >> 2;         // rowgroup: rows 4rp..4rp+3

    __shared__ float weff[H_DIM * D_DIM];   // [h][d]; reads are 4-address broadcast, conflict-free
    __shared__ float qrow[D_DIM];
    __shared__ float qw[H_DIM];
    __shared__ float sacc[4 * D_DIM];       // qW scratch, then per-wave output partials
    __shared__ float red[8];                // per-wave {m, l}

    const size_t fbase = (size_t)b * (T_DIM * D_DIM);
    const int dof = 4 * hq;

    int  rowi[4]; bool mv[4];
    #pragma unroll
    for (int j = 0; j < 4; ++j) {
        int r = 4 * rp + j;
        mv[j]   = (r < T_DIM);
        rowi[j] = mv[j] ? r : (T_DIM - 1);
    }

    // ---- facts -> registers (issued first; latency hides under prologue) ----
    float4 fr[4][8];
    #pragma unroll
    for (int j = 0; j < 4; ++j)
        #pragma unroll
        for (int k = 0; k < 8; ++k)
            fr[j][k] = *(const float4*)&facts[fbase + (size_t)rowi[j] * D_DIM + 16 * k + dof];

    #pragma unroll
    for (int j = 0; j < 4; ++j)
        if (mv[j]) mv[j] = (mask[(size_t)b * T_DIM + rowi[j]] != 0);

    if (tid < D_DIM) qrow[tid] = query[(size_t)b * D_DIM + tid];
    __syncthreads();                                   // B1: qrow ready

    // ---- W_eff[h][d] = (W1b - W1c)[d][h] + q_d * W1d[d][h] ----
    #pragma unroll
    for (int kk = 0; kk < 8; ++kk) {
        int idx = tid + 256 * kk;                      // = h*128 + d
        int d = idx & 127, h = idx >> 7;
        weff[idx] = W1[(128 + d) * H_DIM + h] - W1[(256 + d) * H_DIM + h]
                  + qrow[d] * W1[(384 + d) * H_DIM + h];
    }
    {   // qW partials
        int h = tid & 15, g = tid >> 4;
        float p = 0.f;
        #pragma unroll
        for (int j2 = 0; j2 < 8; ++j2) {
            int d = 8 * g + j2;
            p += qrow[d] * (W1[d * H_DIM + h] + W1[(256 + d) * H_DIM + h]);
        }
        sacc[tid] = p;
    }
    __syncthreads();                                   // B2
    if (tid < H_DIM) {
        float s = b1[tid];
        #pragma unroll
        for (int g = 0; g < 16; ++g) s += sacc[g * 16 + tid];
        qw[tid] = s;
    }
    __syncthreads();                                   // B3: weff + qw ready

    // ---- scoring: 4 rows x 16 h; partial dots reduced across hq BEFORE sigmoid ----
    float score[4] = {0.f, 0.f, 0.f, 0.f};
    #pragma unroll
    for (int hc = 0; hc < 4; ++hc) {
        float pre[4][4];
        #pragma unroll
        for (int hi = 0; hi < 4; ++hi)
            #pragma unroll
            for (int r = 0; r < 4; ++r) pre[r][hi] = 0.f;
        #pragma unroll
        for (int k = 0; k < 8; ++k) {
            #pragma unroll
            for (int hi = 0; hi < 4; ++hi) {
                float4 w4 = *(const float4*)&weff[(4 * hc + hi) * D_DIM + 16 * k + dof];
                #pragma unroll
                for (int r = 0; r < 4; ++r) {
                    pre[r][hi] += fr[r][k].x * w4.x + fr[r][k].y * w4.y
                                + fr[r][k].z * w4.z + fr[r][k].w * w4.w;
                }
            }
        }
        #pragma unroll
        for (int hi = 0; hi < 4; ++hi) {
            float q0  = qw[4 * hc + hi];
            float w2v = W2[4 * hc + hi];
            #pragma unroll
            for (int r = 0; r < 4; ++r) {
                float p = pre[r][hi];
                p += __shfl_xor(p, 1);                 // sum the 4 d-subsets
                p += __shfl_xor(p, 2);                 // (exact: IEEE add commutes -> bit-identical on all lanes)
                score[r] += w2v / (1.f + __expf(-(q0 + p)));
            }
        }
    }
    #pragma unroll
    for (int r = 0; r < 4; ++r)
        if (!mv[r]) score[r] = -1e30f;

    // ---- per-wave single-shot softmax over its 64 rows ----
    float mloc = fmaxf(fmaxf(score[0], score[1]), fmaxf(score[2], score[3]));
    #pragma unroll
    for (int off = 4; off <= 32; off <<= 1) mloc = fmaxf(mloc, __shfl_xor(mloc, off));
    float w[4], ls = 0.f;
    #pragma unroll
    for (int r = 0; r < 4; ++r) {
        w[r] = mv[r] ? __expf(score[r] - mloc) : 0.f;
        ls += w[r];
    }
    #pragma unroll
    for (int off = 4; off <= 32; off <<= 1) ls += __shfl_xor(ls, off);

    // ---- weighted accumulate straight from registers ----
    float4 acc[8];
    #pragma unroll
    for (int k = 0; k < 8; ++k) {
        acc[k].x = w[0]*fr[0][k].x + w[1]*fr[1][k].x + w[2]*fr[2][k].x + w[3]*fr[3][k].x;
        acc[k].y = w[0]*fr[0][k].y + w[1]*fr[1][k].y + w[2]*fr[2][k].y + w[3]*fr[3][k].y;
        acc[k].z = w[0]*fr[0][k].z + w[1]*fr[1][k].z + w[2]*fr[2][k].z + w[3]*fr[3][k].z;
        acc[k].w = w[0]*fr[0][k].w + w[1]*fr[1][k].w + w[2]*fr[2][k].w + w[3]*fr[3][k].w;
    }

    // ---- reduce acc across the wave's 16 rowgroups (butterfly) ----
    #pragma unroll
    for (int off = 4; off <= 32; off <<= 1) {
        #pragma unroll
        for (int k = 0; k < 8; ++k) {
            acc[k].x += __shfl_xor(acc[k].x, off);
            acc[k].y += __shfl_xor(acc[k].y, off);
            acc[k].z += __shfl_xor(acc[k].z, off);
            acc[k].w += __shfl_xor(acc[k].w, off);
        }
    }
    if (lane < 4) {                                    // one lane per hq per wave
        #pragma unroll
        for (int k = 0; k < 8; ++k)
            *(float4*)&sacc[wid * D_DIM + 16 * k + dof] = acc[k];
        if (hq == 0) { red[wid] = mloc; red[4 + wid] = ls; }
    }
    __syncthreads();                                   // B4

    // ---- merge 4 wave partials ----
    if (tid < D_DIM) {
        float m0 = red[0], m1 = red[1], m2 = red[2], m3 = red[3];
        float M  = fmaxf(fmaxf(m0, m1), fmaxf(m2, m3));
        float e0 = __expf(m0 - M), e1 = __expf(m1 - M);
        float e2 = __expf(m2 - M), e3 = __expf(m3 - M);
        float L  = e0 * red[4] + e1 * red[5] + e2 * red[6] + e3 * red[7];
        float o  = e0 * sacc[tid] + e1 * sacc[128 + tid]
                 + e2 * sacc[256 + tid] + e3 * sacc[384 + tid];
        out[(size_t)b * D_DIM + tid] = o / L;
    }
}

extern "C" void kernel_launch(void* const* d_in, const int* in_sizes, int n_in,
                              void* d_out, int out_size, void* d_ws, size_t ws_size,
                              hipStream_t stream) {
    const float* query = (const float*)d_in[0];
    const float* facts = (const float*)d_in[1];
    const int*   mask  = (const int*)d_in[2];   // harness delivers bool as int32
    const float* W1    = (const float*)d_in[3];
    const float* b1    = (const float*)d_in[4];
    const float* W2    = (const float*)d_in[5];
    // d_in[6] = b2: dropped (softmax shift-invariant)
    float* out = (float*)d_out;
    (void)in_sizes; (void)n_in; (void)out_size; (void)d_ws; (void)ws_size;

    din_fused<<<dim3(B_DIM), dim3(256), 0, stream>>>(
        query, facts, mask, W1, b1, W2, out);
}